// Round 13
// baseline (3445.655 us; speedup 1.0000x reference)
//
#include <hip/hip_runtime.h>
#include <hip/hip_bf16.h>
#include <math.h>

// Problem constants: V=96, D=128, T=64, H=8, HD=16, FF=512, L=4, B=4096
#define PREP_THR 512

typedef __attribute__((ext_vector_type(8))) short bf16x8;
typedef __attribute__((ext_vector_type(4))) short bf16x4;
typedef __attribute__((ext_vector_type(4))) float f32x4;

#define MFMA32(a, b, c) __builtin_amdgcn_mfma_f32_16x16x32_bf16((a), (b), (c), 0, 0, 0)

#if defined(__has_builtin)
#if __has_builtin(__builtin_amdgcn_mfma_f32_16x16x16bf16_1k)
#define HAVE_MFMA16 1
#endif
#endif
#ifdef HAVE_MFMA16
#define MFMA16(a, b, c) __builtin_amdgcn_mfma_f32_16x16x16bf16_1k((a), (b), (c), 0, 0, 0)
#else
__device__ __forceinline__ f32x4 mfma16_fb(bf16x4 a, bf16x4 b, f32x4 c) {
  asm volatile("s_nop 1\n\tv_mfma_f32_16x16x16_bf16 %0, %1, %2, %0\n\ts_nop 7\n\ts_nop 7"
               : "+v"(c) : "v"(a), "v"(b));
  return c;
}
#define MFMA16(a, b, c) mfma16_fb((a), (b), (c))
#endif

// ---- workspace layout (bf16 element offsets) ----
// weights pre-converted to bf16, swizzled [K/8][N][8]: dst[(k>>3)*N*8 + n*8 + (k&7)] = W[n][k]
#define WS_EMB 0                      // [96][128]
#define WS_WQ  12288                  // 4x[128][128]
#define WS_WK  (WS_WQ + 65536)
#define WS_WV  (WS_WK + 65536)
#define WS_WO  (WS_WV + 65536)
#define WS_W1  (WS_WO + 65536)        // 4x[512][128]
#define WS_W2  (WS_W1 + 262144)       // 4x[128][512]
#define WS_END (WS_W2 + 262144)

__device__ __forceinline__ short f2bf(float f) {
  union { __hip_bfloat16 h; unsigned short s; } u;
  u.h = __float2bfloat16(f);
  return (short)u.s;
}
__device__ __forceinline__ bf16x4 pk4(f32x4 v) {
  bf16x4 r;
  r[0] = f2bf(v[0]); r[1] = f2bf(v[1]); r[2] = f2bf(v[2]); r[3] = f2bf(v[3]);
  return r;
}
__device__ __forceinline__ float gelu1(float x) {
  float y = x * __builtin_fmaf(0.0356774081f, x * x, 0.7978845608f);
  return x * __builtin_amdgcn_rcpf(1.f + exp2f(-2.885390082f * y));
}

__global__ void prep_weights(const float* __restrict__ tok_emb,
                             const float* __restrict__ Wq, const float* __restrict__ Wk,
                             const float* __restrict__ Wv, const float* __restrict__ Wo,
                             const float* __restrict__ W1, const float* __restrict__ W2,
                             short* __restrict__ wsb) {
  int i = blockIdx.x * PREP_THR + threadIdx.x;
  if (i < 12288) {                       // tok_emb [96][128]
    int n = i >> 7, k = i & 127;
    wsb[WS_EMB + (k >> 3) * 768 + n * 8 + (k & 7)] = f2bf(tok_emb[i]);
    return;
  }
  i -= 12288;
  if (i < 262144) {                      // Wq,Wk,Wv,Wo: [4][128][128] each
    int tensor = i >> 16;
    int rem = i & 65535;
    int l = rem >> 14;
    int w = rem & 16383;
    int n = w >> 7, k = w & 127;
    const float* src = tensor == 0 ? Wq : tensor == 1 ? Wk : tensor == 2 ? Wv : Wo;
    wsb[WS_WQ + tensor * 65536 + l * 16384 + (k >> 3) * 1024 + n * 8 + (k & 7)] =
        f2bf(src[rem]);
    return;
  }
  i -= 262144;
  if (i < 262144) {                      // W1 [4][512][128]
    int l = i >> 16;
    int w = i & 65535;
    int n = w >> 7, k = w & 127;
    wsb[WS_W1 + l * 65536 + (k >> 3) * 4096 + n * 8 + (k & 7)] = f2bf(W1[i]);
    return;
  }
  i -= 262144;
  if (i < 262144) {                      // W2 [4][128][512]
    int l = i >> 16;
    int w = i & 65535;
    int n = w >> 9, k = w & 511;
    wsb[WS_W2 + l * 65536 + (k >> 3) * 1024 + n * 8 + (k & 7)] = f2bf(W2[i]);
  }
}

// One block per sequence, 256 threads = 4 waves, 2 blocks/CU (LDS 54.5 KB).
// TOKEN-PARTITIONED: wave w owns tokens w*16..w*16+15, all 128 dims.
// Residual in regs: x[t][r] = X[token w*16+lr][dim t*16+lg*4+r], t=0..7.
//  - LN fully wave-local (in-thread + shfl_xor 16/32): 0 LDS, 0 barriers.
//  - xn/att/h staging buffers are wave-private rows: no barriers.
//  - Only K/V staging is cross-wave: 3 barriers/layer (vs ~9 in R10).
//  - Wo/FF2 MFMAs accumulate directly into residual regs (D-layout == x-layout).
__global__ __launch_bounds__(256, 2)
void lm_forward(const int* __restrict__ idx, const int* __restrict__ targets,
                const float* __restrict__ tok_emb, const float* __restrict__ pos_emb,
                const float* __restrict__ bo, const float* __restrict__ ln1_g,
                const float* __restrict__ ln1_b, const float* __restrict__ ln2_g,
                const float* __restrict__ ln2_b, const float* __restrict__ b1,
                const float* __restrict__ b2, const float* __restrict__ lnf_g,
                const float* __restrict__ lnf_b, const float* __restrict__ lm_b,
                const short* __restrict__ wsb, float* __restrict__ out,
                float* __restrict__ loss_part) {
  __shared__ __align__(16) short sXn[64 * 136];   // 17408 B, wave-private rows
  __shared__ __align__(16) char regionB[36864];   // sKT[64][136] + sVT[128][76]
  __shared__ float sRed[64];
  short* sKT = (short*)regionB;                   // [64][136] K [token][dim]
  short* sVT = (short*)(regionB + 17408);         // [128][76] V^T [dim][token]
  short* sAw = (short*)regionB;                   // att bounce (after attention)
  short* sH  = (short*)(regionB + 18432);         // [64][136] FF hidden chunk

  const int b = blockIdx.x;
  const int tid = threadIdx.x;
  const int w = tid >> 6;          // wave = token tile
  const int lane = tid & 63;
  const int lr = lane & 15;
  const int lg = lane >> 4;
  const int myrow = w * 16 + lr;   // own token
  const f32x4 fz = {0.f, 0.f, 0.f, 0.f};
  const float KSC = 0.360673760f;  // 0.25 * log2(e)

  // ---- embedding: residual regs (D-layout) ----
  f32x4 x[8];
  {
    int tk = idx[b * 64 + myrow];
#pragma unroll
    for (int t = 0; t < 8; ++t) {
      int dim = t * 16 + lg * 4;
      x[t] = *(const f32x4*)(tok_emb + tk * 128 + dim) +
             *(const f32x4*)(pos_emb + myrow * 128 + dim);
    }
  }

  // wave-local LN: stats in regs + shfl over the 4 lanes holding this token;
  // writes normalized bf16 to sXn (own row) and returns nothing.
  auto ln = [&](const float* g, const float* be) {
    float s = 0.f, s2 = 0.f;
#pragma unroll
    for (int t = 0; t < 8; ++t)
#pragma unroll
      for (int r = 0; r < 4; ++r) { float v = x[t][r]; s += v; s2 += v * v; }
    s += __shfl_xor(s, 16, 64);  s += __shfl_xor(s, 32, 64);
    s2 += __shfl_xor(s2, 16, 64); s2 += __shfl_xor(s2, 32, 64);
    float mean = s * 0.0078125f;
    float rstd = rsqrtf(__builtin_fmaf(-mean, mean, s2 * 0.0078125f) + 1e-5f);
#pragma unroll
    for (int t = 0; t < 8; ++t) {
      int dim = t * 16 + lg * 4;
      f32x4 g4 = *(const f32x4*)(g + dim);
      f32x4 b4 = *(const f32x4*)(be + dim);
      f32x4 o;
#pragma unroll
      for (int c = 0; c < 4; ++c)
        o[c] = __builtin_fmaf((x[t][c] - mean) * rstd, g4[c], b4[c]);
      *(bf16x4*)(sXn + myrow * 136 + dim) = pk4(o);
    }
  };
  // load the 4 B-fragments of own token (serves QKV / FF1 / logits)
  auto load_xb = [&](bf16x8* xb) {
#pragma unroll
    for (int ks = 0; ks < 4; ++ks)
      xb[ks] = *(const bf16x8*)(sXn + myrow * 136 + ks * 32 + lg * 8);
  };

#pragma unroll 1
  for (int l = 0; l < 4; ++l) {
    ln(ln1_g + l * 128, ln1_b + l * 128);
    bf16x8 xb[4];
    load_xb(xb);

    const short* wq = wsb + WS_WQ + l * 16384;
    const short* wk = wsb + WS_WK + l * 16384;
    const short* wv = wsb + WS_WV + l * 16384;

    // ---- Q pass (transposed orientation; stays in regs as attention B-frags) ----
    bf16x4 qf[8];
    {
      f32x4 aq[8];
#pragma unroll
      for (int h = 0; h < 8; ++h) aq[h] = fz;
#pragma unroll
      for (int ks = 0; ks < 4; ++ks)
#pragma unroll
        for (int h = 0; h < 8; ++h) {
          bf16x8 wf = *(const bf16x8*)(wq + (ks * 4 + lg) * 1024 + (h * 16 + lr) * 8);
          aq[h] = MFMA32(wf, xb[ks], aq[h]);
        }
#pragma unroll
      for (int h = 0; h < 8; ++h) qf[h] = pk4(aq[h] * KSC);
    }
    // ---- K pass -> sKT[token][dim] ----
    {
      f32x4 ak[8];
#pragma unroll
      for (int h = 0; h < 8; ++h) ak[h] = fz;
#pragma unroll
      for (int ks = 0; ks < 4; ++ks)
#pragma unroll
        for (int h = 0; h < 8; ++h) {
          bf16x8 wf = *(const bf16x8*)(wk + (ks * 4 + lg) * 1024 + (h * 16 + lr) * 8);
          ak[h] = MFMA32(wf, xb[ks], ak[h]);
        }
#pragma unroll
      for (int h = 0; h < 8; ++h)
        *(bf16x4*)(sKT + myrow * 136 + h * 16 + lg * 4) = pk4(ak[h]);
    }
    // ---- V pass (normal orientation) -> sVT[dim][token] ----
    {
      f32x4 av[8];
#pragma unroll
      for (int h = 0; h < 8; ++h) av[h] = fz;
#pragma unroll
      for (int ks = 0; ks < 4; ++ks)
#pragma unroll
        for (int h = 0; h < 8; ++h) {
          bf16x8 wf = *(const bf16x8*)(wv + (ks * 4 + lg) * 1024 + (h * 16 + lr) * 8);
          av[h] = MFMA32(xb[ks], wf, av[h]);
        }
#pragma unroll
      for (int h = 0; h < 8; ++h)
        *(bf16x4*)(sVT + (h * 16 + lr) * 76 + w * 16 + lg * 4) = pk4(av[h]);
    }
    __syncthreads();   // K/V visible

    // ---- attention: own query tile vs key tiles m<=w (wave-uniform skip) ----
    bf16x4 ab[8];
#pragma unroll 1
    for (int h = 0; h < 8; ++h) {
      f32x4 sc[4];
#pragma unroll
      for (int m = 0; m < 4; ++m)
        if (m <= w) {
          bf16x4 kfr = *(const bf16x4*)(sKT + (m * 16 + lr) * 136 + h * 16 + lg * 4);
          sc[m] = MFMA16(kfr, qf[h], fz);
          if (m == w) {
#pragma unroll
            for (int r = 0; r < 4; ++r)
              if (lg * 4 + r > lr) sc[m][r] = -1e30f;
          }
        }
      float mx = -1e30f;
#pragma unroll
      for (int m = 0; m < 4; ++m)
        if (m <= w)
#pragma unroll
          for (int r = 0; r < 4; ++r) mx = fmaxf(mx, sc[m][r]);
      mx = fmaxf(mx, __shfl_xor(mx, 16, 64));
      mx = fmaxf(mx, __shfl_xor(mx, 32, 64));
      float sum = 0.f;
#pragma unroll
      for (int m = 0; m < 4; ++m)
        if (m <= w)
#pragma unroll
          for (int r = 0; r < 4; ++r) {
            float p = exp2f(sc[m][r] - mx);
            sc[m][r] = p;
            sum += p;
          }
      sum += __shfl_xor(sum, 16, 64);
      sum += __shfl_xor(sum, 32, 64);
      float rinv = __builtin_amdgcn_rcpf(sum);
      f32x4 ao = fz;
#pragma unroll
      for (int m = 0; m < 4; ++m)
        if (m <= w) {
          bf16x4 vfr = *(const bf16x4*)(sVT + (h * 16 + lr) * 76 + m * 16 + lg * 4);
          bf16x4 pf = pk4(sc[m] * rinv);
          ao = MFMA16(vfr, pf, ao);
        }
      ab[h] = pk4(ao);
    }
    __syncthreads();   // attention reads done; region B reusable

    // ---- att bounce (wave-private) + Wo accumulating into residual ----
    {
#pragma unroll
      for (int h = 0; h < 8; ++h)
        *(bf16x4*)(sAw + myrow * 136 + h * 16 + lg * 4) = ab[h];
      bf16x8 atb[4];
#pragma unroll
      for (int ks = 0; ks < 4; ++ks)
        atb[ks] = *(const bf16x8*)(sAw + myrow * 136 + ks * 32 + lg * 8);
      const short* wo = wsb + WS_WO + l * 16384;
#pragma unroll
      for (int ks = 0; ks < 4; ++ks)
#pragma unroll
        for (int t = 0; t < 8; ++t) {
          bf16x8 wf = *(const bf16x8*)(wo + (ks * 4 + lg) * 1024 + (t * 16 + lr) * 8);
          x[t] = MFMA32(wf, atb[ks], x[t]);
        }
#pragma unroll
      for (int t = 0; t < 8; ++t)
        x[t] = x[t] + *(const f32x4*)(bo + l * 128 + t * 16 + lg * 4);
    }

    ln(ln2_g + l * 128, ln2_b + l * 128);
    load_xb(xb);

    // ---- FF: 4 chunks of 128 hidden; h bounce wave-private; FF2 into residual ----
    {
      const short* w1 = wsb + WS_W1 + l * 65536;
      const short* w2 = wsb + WS_W2 + l * 65536;
#pragma unroll 1
      for (int c = 0; c < 4; ++c) {
        f32x4 a1[8];
#pragma unroll
        for (int t2 = 0; t2 < 8; ++t2) a1[t2] = fz;
#pragma unroll
        for (int ks = 0; ks < 4; ++ks)
#pragma unroll
          for (int t2 = 0; t2 < 8; ++t2) {
            bf16x8 wf = *(const bf16x8*)(w1 + (ks * 4 + lg) * 4096 +
                                         (c * 128 + t2 * 16 + lr) * 8);
            a1[t2] = MFMA32(wf, xb[ks], a1[t2]);
          }
#pragma unroll
        for (int t2 = 0; t2 < 8; ++t2) {
          int hd = c * 128 + t2 * 16 + lg * 4;
          f32x4 b1v = *(const f32x4*)(b1 + l * 512 + hd);
          f32x4 hv;
#pragma unroll
          for (int r = 0; r < 4; ++r) hv[r] = gelu1(a1[t2][r] + b1v[r]);
          *(bf16x4*)(sH + myrow * 136 + t2 * 16 + lg * 4) = pk4(hv);
        }
        bf16x8 hb[4];
#pragma unroll
        for (int ks = 0; ks < 4; ++ks)
          hb[ks] = *(const bf16x8*)(sH + myrow * 136 + ks * 32 + lg * 8);
#pragma unroll
        for (int ks = 0; ks < 4; ++ks)
#pragma unroll
          for (int t = 0; t < 8; ++t) {
            bf16x8 wf = *(const bf16x8*)(w2 + (c * 16 + ks * 4 + lg) * 1024 +
                                         (t * 16 + lr) * 8);
            x[t] = MFMA32(wf, hb[ks], x[t]);
          }
      }
#pragma unroll
      for (int t = 0; t < 8; ++t)
        x[t] = x[t] + *(const f32x4*)(b2 + l * 128 + t * 16 + lg * 4);
    }
    __syncthreads();   // region B (sH) reads done before next layer's K/V stores
  }

  // ---- final LN + logits + CE (all wave-local) ----
  ln(lnf_g, lnf_b);
  {
    bf16x8 xb[4];
    load_xb(xb);
    f32x4 al[6];
#pragma unroll
    for (int vt = 0; vt < 6; ++vt) al[vt] = fz;
#pragma unroll
    for (int ks = 0; ks < 4; ++ks)
#pragma unroll
      for (int vt = 0; vt < 6; ++vt) {
        bf16x8 ef = *(const bf16x8*)(wsb + WS_EMB + (ks * 4 + lg) * 768 +
                                     (vt * 16 + lr) * 8);
        al[vt] = MFMA32(ef, xb[ks], al[vt]);
      }
    int cgt = targets[b * 64 + myrow];
    float mx = -1e30f, tsel = 0.f;
#pragma unroll
    for (int vt = 0; vt < 6; ++vt) {
      f32x4 lb = *(const f32x4*)(lm_b + vt * 16 + lg * 4);
      al[vt] = al[vt] + lb;
      *(f32x4*)(out + ((size_t)b * 64 + myrow) * 96 + vt * 16 + lg * 4) = al[vt];
#pragma unroll
      for (int r = 0; r < 4; ++r) {
        mx = fmaxf(mx, al[vt][r]);
        if ((cgt >> 4) == vt && ((cgt >> 2) & 3) == lg && (cgt & 3) == r)
          tsel = al[vt][r];
      }
    }
    mx = fmaxf(mx, __shfl_xor(mx, 16, 64));
    mx = fmaxf(mx, __shfl_xor(mx, 32, 64));
    float sum = 0.f;
#pragma unroll
    for (int vt = 0; vt < 6; ++vt)
#pragma unroll
      for (int r = 0; r < 4; ++r) sum += __expf(al[vt][r] - mx);
    sum += __shfl_xor(sum, 16, 64);
    sum += __shfl_xor(sum, 32, 64);
    tsel += __shfl_xor(tsel, 16, 64);
    tsel += __shfl_xor(tsel, 32, 64);
    if (lg == 0) sRed[myrow] = mx + logf(sum) - tsel;
  }
  __syncthreads();
  if (w == 0) {
    float v = sRed[lane];
#pragma unroll
    for (int m = 32; m >= 1; m >>= 1) v += __shfl_xor(v, m, 64);
    if (lane == 0) loss_part[b] = v;
  }
}

__global__ void loss_reduce(const float* __restrict__ loss_part, float* __restrict__ out_loss) {
  __shared__ float red[256];
  int t = threadIdx.x;
  float s = 0.f;
  for (int i = t; i < 4096; i += 256) s += loss_part[i];
  red[t] = s;
  __syncthreads();
  for (int k = 128; k >= 1; k >>= 1) {
    if (t < k) red[t] += red[t + k];
    __syncthreads();
  }
  if (t == 0) out_loss[0] = red[0] * (1.f / 262144.f);
}

extern "C" void kernel_launch(void* const* d_in, const int* in_sizes, int n_in,
                              void* d_out, int out_size, void* d_ws, size_t ws_size,
                              hipStream_t stream) {
  (void)in_sizes; (void)n_in; (void)ws_size;
  const int* idx      = (const int*)d_in[0];
  const int* targets  = (const int*)d_in[1];
  const float* tok_emb = (const float*)d_in[2];
  const float* pos_emb = (const float*)d_in[3];
  const float* Wq = (const float*)d_in[4];
  const float* Wk = (const float*)d_in[5];
  const float* Wv = (const float*)d_in[6];
  const float* Wo = (const float*)d_in[7];
  const float* bo = (const float*)d_in[8];
  const float* ln1_g = (const float*)d_in[9];
  const float* ln1_b = (const float*)d_in[10];
  const float* ln2_g = (const float*)d_in[11];
  const float* ln2_b = (const float*)d_in[12];
  const float* W1 = (const float*)d_in[13];
  const float* b1 = (const float*)d_in[14];
  const float* W2 = (const float*)d_in[15];
  const float* b2 = (const float*)d_in[16];
  const float* lnf_g = (const float*)d_in[17];
  const float* lnf_b = (const float*)d_in[18];
  const float* lm_b = (const float*)d_in[19];

  short* wsb = (short*)d_ws;
  float* loss_part = (float*)((char*)d_ws + (size_t)WS_END * 2);
  float* out = (float*)d_out;

  prep_weights<<<1560, PREP_THR, 0, stream>>>(tok_emb, Wq, Wk, Wv, Wo, W1, W2, wsb);
  lm_forward<<<4096, 256, 0, stream>>>(idx, targets, tok_emb, pos_emb, bo,
                                       ln1_g, ln1_b, ln2_g, ln2_b, b1, b2,
                                       lnf_g, lnf_b, lm_b, wsb, out, loss_part);
  loss_reduce<<<1, 256, 0, stream>>>(loss_part, out + (out_size - 1));
}

// Round 14
// 947.303 us; speedup vs baseline: 3.6373x; 3.6373x over previous
//
#include <hip/hip_runtime.h>
#include <hip/hip_bf16.h>
#include <math.h>

// Problem constants: V=96, D=128, T=64, H=8, HD=16, FF=512, L=4, B=4096
#define PREP_THR 512

typedef __attribute__((ext_vector_type(8))) short bf16x8;
typedef __attribute__((ext_vector_type(4))) short bf16x4;
typedef __attribute__((ext_vector_type(4))) float f32x4;

#define MFMA32(a, b, c) __builtin_amdgcn_mfma_f32_16x16x32_bf16((a), (b), (c), 0, 0, 0)

#if defined(__has_builtin)
#if __has_builtin(__builtin_amdgcn_mfma_f32_16x16x16bf16_1k)
#define HAVE_MFMA16 1
#endif
#endif
#ifdef HAVE_MFMA16
#define MFMA16(a, b, c) __builtin_amdgcn_mfma_f32_16x16x16bf16_1k((a), (b), (c), 0, 0, 0)
#else
__device__ __forceinline__ f32x4 mfma16_fb(bf16x4 a, bf16x4 b, f32x4 c) {
  asm volatile("s_nop 1\n\tv_mfma_f32_16x16x16_bf16 %0, %1, %2, %0\n\ts_nop 7\n\ts_nop 7"
               : "+v"(c) : "v"(a), "v"(b));
  return c;
}
#define MFMA16(a, b, c) mfma16_fb((a), (b), (c))
#endif

// ---- workspace layout (bf16 element offsets) ----
// weights pre-converted to bf16, swizzled [K/8][N][8]: dst[(k>>3)*N*8 + n*8 + (k&7)] = W[n][k]
#define WS_EMB 0                      // [96][128]
#define WS_WQ  12288                  // 4x[128][128]
#define WS_WK  (WS_WQ + 65536)
#define WS_WV  (WS_WK + 65536)
#define WS_WO  (WS_WV + 65536)
#define WS_W1  (WS_WO + 65536)        // 4x[512][128]
#define WS_W2  (WS_W1 + 262144)       // 4x[128][512]
#define WS_END (WS_W2 + 262144)

__device__ __forceinline__ short f2bf(float f) {
  union { __hip_bfloat16 h; unsigned short s; } u;
  u.h = __float2bfloat16(f);
  return (short)u.s;
}
__device__ __forceinline__ bf16x4 pk4(f32x4 v) {
  bf16x4 r;
  r[0] = f2bf(v[0]); r[1] = f2bf(v[1]); r[2] = f2bf(v[2]); r[3] = f2bf(v[3]);
  return r;
}
__device__ __forceinline__ float gelu1(float x) {
  float y = x * __builtin_fmaf(0.0356774081f, x * x, 0.7978845608f);
  return x * __builtin_amdgcn_rcpf(1.f + exp2f(-2.885390082f * y));
}

__global__ void prep_weights(const float* __restrict__ tok_emb,
                             const float* __restrict__ Wq, const float* __restrict__ Wk,
                             const float* __restrict__ Wv, const float* __restrict__ Wo,
                             const float* __restrict__ W1, const float* __restrict__ W2,
                             short* __restrict__ wsb) {
  int i = blockIdx.x * PREP_THR + threadIdx.x;
  if (i < 12288) {                       // tok_emb [96][128]
    int n = i >> 7, k = i & 127;
    wsb[WS_EMB + (k >> 3) * 768 + n * 8 + (k & 7)] = f2bf(tok_emb[i]);
    return;
  }
  i -= 12288;
  if (i < 262144) {                      // Wq,Wk,Wv,Wo: [4][128][128] each
    int tensor = i >> 16;
    int rem = i & 65535;
    int l = rem >> 14;
    int w = rem & 16383;
    int n = w >> 7, k = w & 127;
    const float* src = tensor == 0 ? Wq : tensor == 1 ? Wk : tensor == 2 ? Wv : Wo;
    wsb[WS_WQ + tensor * 65536 + l * 16384 + (k >> 3) * 1024 + n * 8 + (k & 7)] =
        f2bf(src[rem]);
    return;
  }
  i -= 262144;
  if (i < 262144) {                      // W1 [4][512][128]
    int l = i >> 16;
    int w = i & 65535;
    int n = w >> 7, k = w & 127;
    wsb[WS_W1 + l * 65536 + (k >> 3) * 4096 + n * 8 + (k & 7)] = f2bf(W1[i]);
    return;
  }
  i -= 262144;
  if (i < 262144) {                      // W2 [4][128][512]
    int l = i >> 16;
    int w = i & 65535;
    int n = w >> 9, k = w & 511;
    wsb[WS_W2 + l * 65536 + (k >> 3) * 1024 + n * 8 + (k & 7)] = f2bf(W2[i]);
  }
}

// One block per sequence, 256 threads = 4 waves; target 3 blocks/CU.
// R10 structure (869us, spill-free) + register trims to fit 12 waves/CU:
//  - FF1 in 2 g-passes (acc 64 -> 32)
//  - Wo/FF2 accumulate MFMA directly into residual regs (deletes ac/a2, -48 regs)
//  - __launch_bounds__(256,3): arch cap 2048/12 ~= 170 (proven min-blocks semantics)
// LDS 53.75 KB x 3 = 161.25 KB <= 160... (LDS_Block_Size 53760*3=161280 < 163840 OK).
// Wave owns 32 dims (2 heads). x[cg][n][r] = X^T[wave*32+cg*16+lg*4+r][16n+lr].
__global__ __launch_bounds__(256, 3)
void lm_forward(const int* __restrict__ idx, const int* __restrict__ targets,
                const float* __restrict__ tok_emb, const float* __restrict__ pos_emb,
                const float* __restrict__ bo, const float* __restrict__ ln1_g,
                const float* __restrict__ ln1_b, const float* __restrict__ ln2_g,
                const float* __restrict__ ln2_b, const float* __restrict__ b1,
                const float* __restrict__ b2, const float* __restrict__ lnf_g,
                const float* __restrict__ lnf_b, const float* __restrict__ lm_b,
                const short* __restrict__ wsb, float* __restrict__ out,
                float* __restrict__ loss_part) {
  __shared__ __align__(16) short sXn[64 * 136];      // 17408 B (LN out)
  __shared__ __align__(16) char region[33792];       // sAtt[64][136] / sH[64][264] / sL[64][100]f32
  __shared__ __align__(16) float sPart[4 * 64 * 2];  // 2048 B LN partials
  __shared__ float sRed[64];
  short* sAtt = (short*)region;
  short* sH = (short*)region;
  float* sL = (float*)region;

  const int b = blockIdx.x;
  const int tid = threadIdx.x;
  const int wave = tid >> 6;       // 0..3
  const int lane = tid & 63;
  const int lr = lane & 15;
  const int lg = lane >> 4;
  const f32x4 fz = {0.f, 0.f, 0.f, 0.f};
  const float KSC = 0.360673760f;  // 0.25 * log2(e)

  // ---- embedding: residual regs (wave owns dims wave*32 .. +31) ----
  f32x4 x[2][4];
#pragma unroll
  for (int cg = 0; cg < 2; ++cg)
#pragma unroll
    for (int n = 0; n < 4; ++n) {
      int t = 16 * n + lr;
      int dim = wave * 32 + cg * 16 + lg * 4;
      int tk = idx[b * 64 + t];
      x[cg][n] = *(const f32x4*)(tok_emb + tk * 128 + dim) +
                 *(const f32x4*)(pos_emb + t * 128 + dim);
    }

  // LN on reg residual; 2 barriers; writes sXn.
  auto ln = [&](const float* g, const float* be) {
    float s[4], s2[4];
#pragma unroll
    for (int n = 0; n < 4; ++n) {
      float a = 0.f, a2 = 0.f;
#pragma unroll
      for (int cg = 0; cg < 2; ++cg)
#pragma unroll
        for (int r = 0; r < 4; ++r) {
          float v = x[cg][n][r];
          a += v; a2 += v * v;
        }
      s[n] = a; s2[n] = a2;
    }
#pragma unroll
    for (int n = 0; n < 4; ++n) {
      s[n] += __shfl_xor(s[n], 16, 64);  s[n] += __shfl_xor(s[n], 32, 64);
      s2[n] += __shfl_xor(s2[n], 16, 64); s2[n] += __shfl_xor(s2[n], 32, 64);
    }
    if (lg == 0) {
#pragma unroll
      for (int n = 0; n < 4; ++n) {
        float2 p; p.x = s[n]; p.y = s2[n];
        *(float2*)(sPart + (wave * 64 + 16 * n + lr) * 2) = p;
      }
    }
    __syncthreads();
    f32x4 g4[2], b4[2];
#pragma unroll
    for (int cg = 0; cg < 2; ++cg) {
      int dim = wave * 32 + cg * 16 + lg * 4;
      g4[cg] = *(const f32x4*)(g + dim);
      b4[cg] = *(const f32x4*)(be + dim);
    }
#pragma unroll
    for (int n = 0; n < 4; ++n) {
      float S = 0.f, S2 = 0.f;
#pragma unroll
      for (int w = 0; w < 4; ++w) {
        float2 p = *(const float2*)(sPart + (w * 64 + 16 * n + lr) * 2);
        S += p.x; S2 += p.y;
      }
      float mean = S * 0.0078125f;
      float rstd = rsqrtf(__builtin_fmaf(-mean, mean, S2 * 0.0078125f) + 1e-5f);
#pragma unroll
      for (int cg = 0; cg < 2; ++cg) {
        f32x4 o;
#pragma unroll
        for (int c = 0; c < 4; ++c)
          o[c] = __builtin_fmaf((x[cg][n][c] - mean) * rstd, g4[cg][c], b4[cg][c]);
        *(bf16x4*)(sXn + (16 * n + lr) * 136 + wave * 32 + cg * 16 + lg * 4) = pk4(o);
      }
    }
    __syncthreads();
  };

#pragma unroll 1
  for (int l = 0; l < 4; ++l) {
    ln(ln1_g + l * 128, ln1_b + l * 128);

    // ---- QKV + attention, per head (wave owns heads 2*wave, 2*wave+1) ----
    const short* wq = wsb + WS_WQ + l * 16384;
    const short* wk = wsb + WS_WK + l * 16384;
    const short* wv = wsb + WS_WV + l * 16384;
#pragma unroll
    for (int hs = 0; hs < 2; ++hs) {
      const int h = wave * 2 + hs;
      f32x4 aq[4], ak[4], av[4];
#pragma unroll
      for (int n = 0; n < 4; ++n) { aq[n] = fz; ak[n] = fz; av[n] = fz; }
#pragma unroll
      for (int ks = 0; ks < 4; ++ks) {
        bf16x8 xf[4];
#pragma unroll
        for (int n = 0; n < 4; ++n)
          xf[n] = *(const bf16x8*)(sXn + (16 * n + lr) * 136 + ks * 32 + lg * 8);
        int wo_ = (ks * 4 + lg) * 1024 + (h * 16 + lr) * 8;
        bf16x8 qw = *(const bf16x8*)(wq + wo_);
        bf16x8 kw = *(const bf16x8*)(wk + wo_);
        bf16x8 vw = *(const bf16x8*)(wv + wo_);
#pragma unroll
        for (int n = 0; n < 4; ++n) {
          aq[n] = MFMA32(qw, xf[n], aq[n]);
          ak[n] = MFMA32(kw, xf[n], ak[n]);
          av[n] = MFMA32(xf[n], vw, av[n]);
        }
      }
      bf16x4 qf[4], kf[4], vf[4];
#pragma unroll
      for (int n = 0; n < 4; ++n) {
        qf[n] = pk4(aq[n] * KSC);
        kf[n] = pk4(ak[n]);
        vf[n] = pk4(av[n]);
      }
      // in-register attention, causal tile-skip (verified R7/R10)
      f32x4 sc[4][4];
#pragma unroll
      for (int n = 0; n < 4; ++n)
#pragma unroll
        for (int m = 0; m <= n; ++m)
          sc[m][n] = MFMA16(kf[m], qf[n], fz);
#pragma unroll
      for (int n = 0; n < 4; ++n) {
#pragma unroll
        for (int r = 0; r < 4; ++r)
          if (lg * 4 + r > lr) sc[n][n][r] = -1e30f;
        float mx = -1e30f;
#pragma unroll
        for (int m = 0; m <= n; ++m)
#pragma unroll
          for (int r = 0; r < 4; ++r) mx = fmaxf(mx, sc[m][n][r]);
        mx = fmaxf(mx, __shfl_xor(mx, 16, 64));
        mx = fmaxf(mx, __shfl_xor(mx, 32, 64));
        float sum = 0.f;
#pragma unroll
        for (int m = 0; m <= n; ++m)
#pragma unroll
          for (int r = 0; r < 4; ++r) {
            float p = exp2f(sc[m][n][r] - mx);
            sc[m][n][r] = p;
            sum += p;
          }
        sum += __shfl_xor(sum, 16, 64);
        sum += __shfl_xor(sum, 32, 64);
        float rinv = __builtin_amdgcn_rcpf(sum);
        f32x4 ao = fz;
#pragma unroll
        for (int m = 0; m <= n; ++m) {
          bf16x4 pf = pk4(sc[m][n] * rinv);
          ao = MFMA16(vf[m], pf, ao);
        }
        *(bf16x4*)(sAtt + (16 * n + lr) * 136 + h * 16 + lg * 4) = pk4(ao);
      }
    }
    __syncthreads();

    // ---- Wo: accumulate directly into residual regs (cols wave*32..+31) ----
    {
      const short* wo = wsb + WS_WO + l * 16384;
#pragma unroll
      for (int ks = 0; ks < 4; ++ks) {
        bf16x8 af[4];
#pragma unroll
        for (int n = 0; n < 4; ++n)
          af[n] = *(const bf16x8*)(sAtt + (16 * n + lr) * 136 + ks * 32 + lg * 8);
#pragma unroll
        for (int cg = 0; cg < 2; ++cg) {
          bf16x8 wf = *(const bf16x8*)(wo + (ks * 4 + lg) * 1024 +
                                       (wave * 32 + cg * 16 + lr) * 8);
#pragma unroll
          for (int n = 0; n < 4; ++n) x[cg][n] = MFMA32(wf, af[n], x[cg][n]);
        }
      }
#pragma unroll
      for (int cg = 0; cg < 2; ++cg) {
        f32x4 bo4 = *(const f32x4*)(bo + l * 128 + wave * 32 + cg * 16 + lg * 4);
#pragma unroll
        for (int n = 0; n < 4; ++n) x[cg][n] = x[cg][n] + bo4;
      }
    }

    ln(ln2_g + l * 128, ln2_b + l * 128);

    // ---- FF: 2 hidden chunks of 256; FF1 in 2 g-passes (acc 32);
    //      FF2 accumulates directly into residual regs ----
    {
      const short* w1 = wsb + WS_W1 + l * 65536;
      const short* w2 = wsb + WS_W2 + l * 65536;
#pragma unroll 1
      for (int c = 0; c < 2; ++c) {
#pragma unroll 1
        for (int g2 = 0; g2 < 2; ++g2) {
          f32x4 a1[2][4];
#pragma unroll
          for (int gg = 0; gg < 2; ++gg)
#pragma unroll
            for (int n = 0; n < 4; ++n) a1[gg][n] = fz;
#pragma unroll
          for (int ks = 0; ks < 4; ++ks) {
            bf16x8 xf[4];
#pragma unroll
            for (int n = 0; n < 4; ++n)
              xf[n] = *(const bf16x8*)(sXn + (16 * n + lr) * 136 + ks * 32 + lg * 8);
#pragma unroll
            for (int gg = 0; gg < 2; ++gg) {
              bf16x8 wf = *(const bf16x8*)(w1 + (ks * 4 + lg) * 4096 +
                                           (c * 256 + wave * 64 + (g2 * 2 + gg) * 16 + lr) * 8);
#pragma unroll
              for (int n = 0; n < 4; ++n) a1[gg][n] = MFMA32(wf, xf[n], a1[gg][n]);
            }
          }
#pragma unroll
          for (int gg = 0; gg < 2; ++gg) {
            f32x4 b1v = *(const f32x4*)(b1 + l * 512 + c * 256 + wave * 64 +
                                        (g2 * 2 + gg) * 16 + lg * 4);
#pragma unroll
            for (int n = 0; n < 4; ++n) {
              f32x4 hv;
#pragma unroll
              for (int r = 0; r < 4; ++r) hv[r] = gelu1(a1[gg][n][r] + b1v[r]);
              *(bf16x4*)(sH + (16 * n + lr) * 264 + wave * 64 +
                         (g2 * 2 + gg) * 16 + lg * 4) = pk4(hv);
            }
          }
        }
        __syncthreads();
#pragma unroll
        for (int ks = 0; ks < 8; ++ks) {
          bf16x8 hf[4];
#pragma unroll
          for (int n = 0; n < 4; ++n)
            hf[n] = *(const bf16x8*)(sH + (16 * n + lr) * 264 + ks * 32 + lg * 8);
#pragma unroll
          for (int cg = 0; cg < 2; ++cg) {
            bf16x8 wf = *(const bf16x8*)(w2 + (c * 32 + ks * 4 + lg) * 1024 +
                                         (wave * 32 + cg * 16 + lr) * 8);
#pragma unroll
            for (int n = 0; n < 4; ++n) x[cg][n] = MFMA32(wf, hf[n], x[cg][n]);
          }
        }
        if (c == 0) __syncthreads();
      }
#pragma unroll
      for (int cg = 0; cg < 2; ++cg) {
        f32x4 b2v = *(const f32x4*)(b2 + l * 128 + wave * 32 + cg * 16 + lg * 4);
#pragma unroll
        for (int n = 0; n < 4; ++n) x[cg][n] = x[cg][n] + b2v;
      }
    }
  }

  // ---- final LN ----
  ln(lnf_g, lnf_b);

  // ---- logits: vocab tiles {wave} + {wave+4 if wave<2} ----
  {
    auto do_tile = [&](int vt) {
      f32x4 al[4];
#pragma unroll
      for (int n = 0; n < 4; ++n) al[n] = fz;
#pragma unroll
      for (int ks = 0; ks < 4; ++ks) {
        bf16x8 ef = *(const bf16x8*)(wsb + WS_EMB + (ks * 4 + lg) * 768 +
                                     (vt * 16 + lr) * 8);
#pragma unroll
        for (int n = 0; n < 4; ++n) {
          bf16x8 xf = *(const bf16x8*)(sXn + (16 * n + lr) * 136 + ks * 32 + lg * 8);
          al[n] = MFMA32(ef, xf, al[n]);
        }
      }
      f32x4 lb = *(const f32x4*)(lm_b + vt * 16 + lg * 4);
#pragma unroll
      for (int n = 0; n < 4; ++n) {
        f32x4 v = al[n] + lb;
        int t = 16 * n + lr;
        *(f32x4*)(out + ((size_t)b * 64 + t) * 96 + vt * 16 + lg * 4) = v;
        *(f32x4*)(sL + t * 100 + vt * 16 + lg * 4) = v;
      }
    };
    do_tile(wave);
    if (wave < 2) do_tile(wave + 4);
  }
  __syncthreads();

  // ---- per-row cross-entropy (4 threads/row, 24 cols each) ----
  {
    int r = tid >> 2, c4 = tid & 3;
    const float* lrow = sL + r * 100 + c4 * 24;
    float mx = -1e30f;
#pragma unroll
    for (int j = 0; j < 24; ++j) mx = fmaxf(mx, lrow[j]);
    mx = fmaxf(mx, __shfl_xor(mx, 1, 64));
    mx = fmaxf(mx, __shfl_xor(mx, 2, 64));
    float sum = 0.f;
#pragma unroll
    for (int j = 0; j < 24; ++j) sum += __expf(lrow[j] - mx);
    sum += __shfl_xor(sum, 1, 64);
    sum += __shfl_xor(sum, 2, 64);
    if (c4 == 0) {
      float lse = logf(sum) + mx;
      sRed[r] = lse - sL[r * 100 + targets[b * 64 + r]];
    }
  }
  __syncthreads();
  if (wave == 0) {
    float v = sRed[lane];
#pragma unroll
    for (int m = 32; m >= 1; m >>= 1) v += __shfl_xor(v, m, 64);
    if (lane == 0) loss_part[b] = v;
  }
}

__global__ void loss_reduce(const float* __restrict__ loss_part, float* __restrict__ out_loss) {
  __shared__ float red[256];
  int t = threadIdx.x;
  float s = 0.f;
  for (int i = t; i < 4096; i += 256) s += loss_part[i];
  red[t] = s;
  __syncthreads();
  for (int k = 128; k >= 1; k >>= 1) {
    if (t < k) red[t] += red[t + k];
    __syncthreads();
  }
  if (t == 0) out_loss[0] = red[0] * (1.f / 262144.f);
}

extern "C" void kernel_launch(void* const* d_in, const int* in_sizes, int n_in,
                              void* d_out, int out_size, void* d_ws, size_t ws_size,
                              hipStream_t stream) {
  (void)in_sizes; (void)n_in; (void)ws_size;
  const int* idx      = (const int*)d_in[0];
  const int* targets  = (const int*)d_in[1];
  const float* tok_emb = (const float*)d_in[2];
  const float* pos_emb = (const float*)d_in[3];
  const float* Wq = (const float*)d_in[4];
  const float* Wk = (const float*)d_in[5];
  const float* Wv = (const float*)d_in[6];
  const float* Wo = (const float*)d_in[7];
  const float* bo = (const float*)d_in[8];
  const float* ln1_g = (const float*)d_in[9];
  const float* ln1_b = (const float*)d_in[10];
  const float* ln2_g = (const float*)d_in[11];
  const float* ln2_b = (const float*)d_in[12];
  const float* W1 = (const float*)d_in[13];
  const float* b1 = (const float*)d_in[14];
  const float* W2 = (const float*)d_in[15];
  const float* b2 = (const float*)d_in[16];
  const float* lnf_g = (const float*)d_in[17];
  const float* lnf_b = (const float*)d_in[18];
  const float* lm_b = (const float*)d_in[19];

  short* wsb = (short*)d_ws;
  float* loss_part = (float*)((char*)d_ws + (size_t)WS_END * 2);
  float* out = (float*)d_out;

  prep_weights<<<1560, PREP_THR, 0, stream>>>(tok_emb, Wq, Wk, Wv, Wo, W1, W2, wsb);
  lm_forward<<<4096, 256, 0, stream>>>(idx, targets, tok_emb, pos_emb, bo,
                                       ln1_g, ln1_b, ln2_g, ln2_b, b1, b2,
                                       lnf_g, lnf_b, lm_b, wsb, out, loss_part);
  loss_reduce<<<1, 256, 0, stream>>>(loss_part, out + (out_size - 1));
}

// Round 15
// 812.385 us; speedup vs baseline: 4.2414x; 1.1661x over previous
//
#include <hip/hip_runtime.h>
#include <hip/hip_bf16.h>
#include <math.h>

// Problem constants: V=96, D=128, T=64, H=8, HD=16, FF=512, L=4, B=4096
#define PREP_THR 512

typedef __attribute__((ext_vector_type(8))) short bf16x8;
typedef __attribute__((ext_vector_type(4))) short bf16x4;
typedef __attribute__((ext_vector_type(4))) float f32x4;

#define MFMA32(a, b, c) __builtin_amdgcn_mfma_f32_16x16x32_bf16((a), (b), (c), 0, 0, 0)

#if defined(__has_builtin)
#if __has_builtin(__builtin_amdgcn_mfma_f32_16x16x16bf16_1k)
#define HAVE_MFMA16 1
#endif
#endif
#ifdef HAVE_MFMA16
#define MFMA16(a, b, c) __builtin_amdgcn_mfma_f32_16x16x16bf16_1k((a), (b), (c), 0, 0, 0)
#else
__device__ __forceinline__ f32x4 mfma16_fb(bf16x4 a, bf16x4 b, f32x4 c) {
  asm volatile("s_nop 1\n\tv_mfma_f32_16x16x16_bf16 %0, %1, %2, %0\n\ts_nop 7\n\ts_nop 7"
               : "+v"(c) : "v"(a), "v"(b));
  return c;
}
#define MFMA16(a, b, c) mfma16_fb((a), (b), (c))
#endif

// ---- workspace layout (bf16 element offsets) ----
// weights pre-converted to bf16, swizzled [K/8][N][8]: dst[(k>>3)*N*8 + n*8 + (k&7)] = W[n][k]
#define WS_EMB 0                      // [96][128]
#define WS_WQ  12288                  // 4x[128][128]
#define WS_WK  (WS_WQ + 65536)
#define WS_WV  (WS_WK + 65536)
#define WS_WO  (WS_WV + 65536)
#define WS_W1  (WS_WO + 65536)        // 4x[512][128]
#define WS_W2  (WS_W1 + 262144)       // 4x[128][512]
#define WS_END (WS_W2 + 262144)

__device__ __forceinline__ short f2bf(float f) {
  union { __hip_bfloat16 h; unsigned short s; } u;
  u.h = __float2bfloat16(f);
  return (short)u.s;
}
__device__ __forceinline__ bf16x4 pk4(f32x4 v) {
  bf16x4 r;
  r[0] = f2bf(v[0]); r[1] = f2bf(v[1]); r[2] = f2bf(v[2]); r[3] = f2bf(v[3]);
  return r;
}
__device__ __forceinline__ float gelu1(float x) {
  float y = x * __builtin_fmaf(0.0356774081f, x * x, 0.7978845608f);
  return x * __builtin_amdgcn_rcpf(1.f + exp2f(-2.885390082f * y));
}

__global__ void prep_weights(const float* __restrict__ tok_emb,
                             const float* __restrict__ Wq, const float* __restrict__ Wk,
                             const float* __restrict__ Wv, const float* __restrict__ Wo,
                             const float* __restrict__ W1, const float* __restrict__ W2,
                             short* __restrict__ wsb) {
  int i = blockIdx.x * PREP_THR + threadIdx.x;
  if (i < 12288) {                       // tok_emb [96][128]
    int n = i >> 7, k = i & 127;
    wsb[WS_EMB + (k >> 3) * 768 + n * 8 + (k & 7)] = f2bf(tok_emb[i]);
    return;
  }
  i -= 12288;
  if (i < 262144) {                      // Wq,Wk,Wv,Wo: [4][128][128] each
    int tensor = i >> 16;
    int rem = i & 65535;
    int l = rem >> 14;
    int w = rem & 16383;
    int n = w >> 7, k = w & 127;
    const float* src = tensor == 0 ? Wq : tensor == 1 ? Wk : tensor == 2 ? Wv : Wo;
    wsb[WS_WQ + tensor * 65536 + l * 16384 + (k >> 3) * 1024 + n * 8 + (k & 7)] =
        f2bf(src[rem]);
    return;
  }
  i -= 262144;
  if (i < 262144) {                      // W1 [4][512][128]
    int l = i >> 16;
    int w = i & 65535;
    int n = w >> 7, k = w & 127;
    wsb[WS_W1 + l * 65536 + (k >> 3) * 4096 + n * 8 + (k & 7)] = f2bf(W1[i]);
    return;
  }
  i -= 262144;
  if (i < 262144) {                      // W2 [4][128][512]
    int l = i >> 16;
    int w = i & 65535;
    int n = w >> 9, k = w & 511;
    wsb[WS_W2 + l * 65536 + (k >> 3) * 1024 + n * 8 + (k & 7)] = f2bf(W2[i]);
  }
}

// One block per sequence, 256 threads = 4 waves; 2 blocks/CU (proven spill-free
// config; every >8-waves/CU attempt spilled, R3-R8/R11-R14). R14 math (passed)
// at (256,2) + VALU cuts:
//  - max-free softmax (scores bounded: |sc| <= ~46 in exp2 domain, fp32/bf16 safe;
//    masked entries exp2(-inf)=0) -> removes 2 serial shfl rounds + ~10 fmax per
//    (n,hs) from the critical path
//  - softmax normalization deferred to post-PV (1/Z applied to ao: 4 muls vs 16,
//    and Z's shfl reduce overlaps the PV MFMAs)
//  - Wo/FF2 accumulate MFMA directly into residual regs; FF1 in 2 g-passes
// Wave owns 32 dims (2 heads). x[cg][n][r] = X^T[wave*32+cg*16+lg*4+r][16n+lr].
__global__ __launch_bounds__(256, 2)
void lm_forward(const int* __restrict__ idx, const int* __restrict__ targets,
                const float* __restrict__ tok_emb, const float* __restrict__ pos_emb,
                const float* __restrict__ bo, const float* __restrict__ ln1_g,
                const float* __restrict__ ln1_b, const float* __restrict__ ln2_g,
                const float* __restrict__ ln2_b, const float* __restrict__ b1,
                const float* __restrict__ b2, const float* __restrict__ lnf_g,
                const float* __restrict__ lnf_b, const float* __restrict__ lm_b,
                const short* __restrict__ wsb, float* __restrict__ out,
                float* __restrict__ loss_part) {
  __shared__ __align__(16) short sXn[64 * 136];      // 17408 B (LN out)
  __shared__ __align__(16) char region[33792];       // sAtt[64][136] / sH[64][264] / sL[64][100]f32
  __shared__ __align__(16) float sPart[4 * 64 * 2];  // 2048 B LN partials
  __shared__ float sRed[64];
  short* sAtt = (short*)region;
  short* sH = (short*)region;
  float* sL = (float*)region;

  const int b = blockIdx.x;
  const int tid = threadIdx.x;
  const int wave = tid >> 6;       // 0..3
  const int lane = tid & 63;
  const int lr = lane & 15;
  const int lg = lane >> 4;
  const f32x4 fz = {0.f, 0.f, 0.f, 0.f};
  const float KSC = 0.360673760f;  // 0.25 * log2(e)

  // ---- embedding: residual regs (wave owns dims wave*32 .. +31) ----
  f32x4 x[2][4];
#pragma unroll
  for (int cg = 0; cg < 2; ++cg)
#pragma unroll
    for (int n = 0; n < 4; ++n) {
      int t = 16 * n + lr;
      int dim = wave * 32 + cg * 16 + lg * 4;
      int tk = idx[b * 64 + t];
      x[cg][n] = *(const f32x4*)(tok_emb + tk * 128 + dim) +
                 *(const f32x4*)(pos_emb + t * 128 + dim);
    }

  // LN on reg residual; 2 barriers; writes sXn.
  auto ln = [&](const float* g, const float* be) {
    float s[4], s2[4];
#pragma unroll
    for (int n = 0; n < 4; ++n) {
      float a = 0.f, a2 = 0.f;
#pragma unroll
      for (int cg = 0; cg < 2; ++cg)
#pragma unroll
        for (int r = 0; r < 4; ++r) {
          float v = x[cg][n][r];
          a += v; a2 += v * v;
        }
      s[n] = a; s2[n] = a2;
    }
#pragma unroll
    for (int n = 0; n < 4; ++n) {
      s[n] += __shfl_xor(s[n], 16, 64);  s[n] += __shfl_xor(s[n], 32, 64);
      s2[n] += __shfl_xor(s2[n], 16, 64); s2[n] += __shfl_xor(s2[n], 32, 64);
    }
    if (lg == 0) {
#pragma unroll
      for (int n = 0; n < 4; ++n) {
        float2 p; p.x = s[n]; p.y = s2[n];
        *(float2*)(sPart + (wave * 64 + 16 * n + lr) * 2) = p;
      }
    }
    __syncthreads();
    f32x4 g4[2], b4[2];
#pragma unroll
    for (int cg = 0; cg < 2; ++cg) {
      int dim = wave * 32 + cg * 16 + lg * 4;
      g4[cg] = *(const f32x4*)(g + dim);
      b4[cg] = *(const f32x4*)(be + dim);
    }
#pragma unroll
    for (int n = 0; n < 4; ++n) {
      float S = 0.f, S2 = 0.f;
#pragma unroll
      for (int w = 0; w < 4; ++w) {
        float2 p = *(const float2*)(sPart + (w * 64 + 16 * n + lr) * 2);
        S += p.x; S2 += p.y;
      }
      float mean = S * 0.0078125f;
      float rstd = rsqrtf(__builtin_fmaf(-mean, mean, S2 * 0.0078125f) + 1e-5f);
#pragma unroll
      for (int cg = 0; cg < 2; ++cg) {
        f32x4 o;
#pragma unroll
        for (int c = 0; c < 4; ++c)
          o[c] = __builtin_fmaf((x[cg][n][c] - mean) * rstd, g4[cg][c], b4[cg][c]);
        *(bf16x4*)(sXn + (16 * n + lr) * 136 + wave * 32 + cg * 16 + lg * 4) = pk4(o);
      }
    }
    __syncthreads();
  };

#pragma unroll 1
  for (int l = 0; l < 4; ++l) {
    ln(ln1_g + l * 128, ln1_b + l * 128);

    // ---- QKV + attention, per head (wave owns heads 2*wave, 2*wave+1) ----
    const short* wq = wsb + WS_WQ + l * 16384;
    const short* wk = wsb + WS_WK + l * 16384;
    const short* wv = wsb + WS_WV + l * 16384;
#pragma unroll
    for (int hs = 0; hs < 2; ++hs) {
      const int h = wave * 2 + hs;
      f32x4 aq[4], ak[4], av[4];
#pragma unroll
      for (int n = 0; n < 4; ++n) { aq[n] = fz; ak[n] = fz; av[n] = fz; }
#pragma unroll
      for (int ks = 0; ks < 4; ++ks) {
        bf16x8 xf[4];
#pragma unroll
        for (int n = 0; n < 4; ++n)
          xf[n] = *(const bf16x8*)(sXn + (16 * n + lr) * 136 + ks * 32 + lg * 8);
        int wo_ = (ks * 4 + lg) * 1024 + (h * 16 + lr) * 8;
        bf16x8 qw = *(const bf16x8*)(wq + wo_);
        bf16x8 kw = *(const bf16x8*)(wk + wo_);
        bf16x8 vw = *(const bf16x8*)(wv + wo_);
#pragma unroll
        for (int n = 0; n < 4; ++n) {
          aq[n] = MFMA32(qw, xf[n], aq[n]);
          ak[n] = MFMA32(kw, xf[n], ak[n]);
          av[n] = MFMA32(xf[n], vw, av[n]);
        }
      }
      bf16x4 qf[4], kf[4], vf[4];
#pragma unroll
      for (int n = 0; n < 4; ++n) {
        qf[n] = pk4(aq[n] * KSC);
        kf[n] = pk4(ak[n]);
        vf[n] = pk4(av[n]);
      }
      // in-register attention: max-free exp2 softmax, deferred 1/Z, causal skip
      f32x4 sc[4][4];
#pragma unroll
      for (int n = 0; n < 4; ++n)
#pragma unroll
        for (int m = 0; m <= n; ++m)
          sc[m][n] = MFMA16(kf[m], qf[n], fz);
#pragma unroll
      for (int n = 0; n < 4; ++n) {
#pragma unroll
        for (int r = 0; r < 4; ++r)
          if (lg * 4 + r > lr) sc[n][n][r] = -1e30f;
        float sum = 0.f;
#pragma unroll
        for (int m = 0; m <= n; ++m)
#pragma unroll
          for (int r = 0; r < 4; ++r) {
            float p = exp2f(sc[m][n][r]);   // bounded: |sc| <= ~46
            sc[m][n][r] = p;
            sum += p;
          }
        // PV with unnormalized P; Z-reduce overlaps the MFMAs
        f32x4 ao = fz;
#pragma unroll
        for (int m = 0; m <= n; ++m) {
          bf16x4 pf = pk4(sc[m][n]);
          ao = MFMA16(vf[m], pf, ao);
        }
        sum += __shfl_xor(sum, 16, 64);
        sum += __shfl_xor(sum, 32, 64);
        float rinv = __builtin_amdgcn_rcpf(sum);
        *(bf16x4*)(sAtt + (16 * n + lr) * 136 + h * 16 + lg * 4) = pk4(ao * rinv);
      }
    }
    __syncthreads();

    // ---- Wo: accumulate directly into residual regs (cols wave*32..+31) ----
    {
      const short* wo = wsb + WS_WO + l * 16384;
#pragma unroll
      for (int ks = 0; ks < 4; ++ks) {
        bf16x8 af[4];
#pragma unroll
        for (int n = 0; n < 4; ++n)
          af[n] = *(const bf16x8*)(sAtt + (16 * n + lr) * 136 + ks * 32 + lg * 8);
#pragma unroll
        for (int cg = 0; cg < 2; ++cg) {
          bf16x8 wf = *(const bf16x8*)(wo + (ks * 4 + lg) * 1024 +
                                       (wave * 32 + cg * 16 + lr) * 8);
#pragma unroll
          for (int n = 0; n < 4; ++n) x[cg][n] = MFMA32(wf, af[n], x[cg][n]);
        }
      }
#pragma unroll
      for (int cg = 0; cg < 2; ++cg) {
        f32x4 bo4 = *(const f32x4*)(bo + l * 128 + wave * 32 + cg * 16 + lg * 4);
#pragma unroll
        for (int n = 0; n < 4; ++n) x[cg][n] = x[cg][n] + bo4;
      }
    }

    ln(ln2_g + l * 128, ln2_b + l * 128);

    // ---- FF: 2 hidden chunks of 256; FF1 in 2 g-passes (acc 32);
    //      FF2 accumulates directly into residual regs ----
    {
      const short* w1 = wsb + WS_W1 + l * 65536;
      const short* w2 = wsb + WS_W2 + l * 65536;
#pragma unroll 1
      for (int c = 0; c < 2; ++c) {
#pragma unroll 1
        for (int g2 = 0; g2 < 2; ++g2) {
          f32x4 a1[2][4];
#pragma unroll
          for (int gg = 0; gg < 2; ++gg)
#pragma unroll
            for (int n = 0; n < 4; ++n) a1[gg][n] = fz;
#pragma unroll
          for (int ks = 0; ks < 4; ++ks) {
            bf16x8 xf[4];
#pragma unroll
            for (int n = 0; n < 4; ++n)
              xf[n] = *(const bf16x8*)(sXn + (16 * n + lr) * 136 + ks * 32 + lg * 8);
#pragma unroll
            for (int gg = 0; gg < 2; ++gg) {
              bf16x8 wf = *(const bf16x8*)(w1 + (ks * 4 + lg) * 4096 +
                                           (c * 256 + wave * 64 + (g2 * 2 + gg) * 16 + lr) * 8);
#pragma unroll
              for (int n = 0; n < 4; ++n) a1[gg][n] = MFMA32(wf, xf[n], a1[gg][n]);
            }
          }
#pragma unroll
          for (int gg = 0; gg < 2; ++gg) {
            f32x4 b1v = *(const f32x4*)(b1 + l * 512 + c * 256 + wave * 64 +
                                        (g2 * 2 + gg) * 16 + lg * 4);
#pragma unroll
            for (int n = 0; n < 4; ++n) {
              f32x4 hv;
#pragma unroll
              for (int r = 0; r < 4; ++r) hv[r] = gelu1(a1[gg][n][r] + b1v[r]);
              *(bf16x4*)(sH + (16 * n + lr) * 264 + wave * 64 +
                         (g2 * 2 + gg) * 16 + lg * 4) = pk4(hv);
            }
          }
        }
        __syncthreads();
#pragma unroll
        for (int ks = 0; ks < 8; ++ks) {
          bf16x8 hf[4];
#pragma unroll
          for (int n = 0; n < 4; ++n)
            hf[n] = *(const bf16x8*)(sH + (16 * n + lr) * 264 + ks * 32 + lg * 8);
#pragma unroll
          for (int cg = 0; cg < 2; ++cg) {
            bf16x8 wf = *(const bf16x8*)(w2 + (c * 32 + ks * 4 + lg) * 1024 +
                                         (wave * 32 + cg * 16 + lr) * 8);
#pragma unroll
            for (int n = 0; n < 4; ++n) x[cg][n] = MFMA32(wf, hf[n], x[cg][n]);
          }
        }
        if (c == 0) __syncthreads();
      }
#pragma unroll
      for (int cg = 0; cg < 2; ++cg) {
        f32x4 b2v = *(const f32x4*)(b2 + l * 128 + wave * 32 + cg * 16 + lg * 4);
#pragma unroll
        for (int n = 0; n < 4; ++n) x[cg][n] = x[cg][n] + b2v;
      }
    }
  }

  // ---- final LN ----
  ln(lnf_g, lnf_b);

  // ---- logits: vocab tiles {wave} + {wave+4 if wave<2} ----
  {
    auto do_tile = [&](int vt) {
      f32x4 al[4];
#pragma unroll
      for (int n = 0; n < 4; ++n) al[n] = fz;
#pragma unroll
      for (int ks = 0; ks < 4; ++ks) {
        bf16x8 ef = *(const bf16x8*)(wsb + WS_EMB + (ks * 4 + lg) * 768 +
                                     (vt * 16 + lr) * 8);
#pragma unroll
        for (int n = 0; n < 4; ++n) {
          bf16x8 xf = *(const bf16x8*)(sXn + (16 * n + lr) * 136 + ks * 32 + lg * 8);
          al[n] = MFMA32(ef, xf, al[n]);
        }
      }
      f32x4 lb = *(const f32x4*)(lm_b + vt * 16 + lg * 4);
#pragma unroll
      for (int n = 0; n < 4; ++n) {
        f32x4 v = al[n] + lb;
        int t = 16 * n + lr;
        *(f32x4*)(out + ((size_t)b * 64 + t) * 96 + vt * 16 + lg * 4) = v;
        *(f32x4*)(sL + t * 100 + vt * 16 + lg * 4) = v;
      }
    };
    do_tile(wave);
    if (wave < 2) do_tile(wave + 4);
  }
  __syncthreads();

  // ---- per-row cross-entropy (4 threads/row, 24 cols each) ----
  {
    int r = tid >> 2, c4 = tid & 3;
    const float* lrow = sL + r * 100 + c4 * 24;
    float mx = -1e30f;
#pragma unroll
    for (int j = 0; j < 24; ++j) mx = fmaxf(mx, lrow[j]);
    mx = fmaxf(mx, __shfl_xor(mx, 1, 64));
    mx = fmaxf(mx, __shfl_xor(mx, 2, 64));
    float sum = 0.f;
#pragma unroll
    for (int j = 0; j < 24; ++j) sum += __expf(lrow[j] - mx);
    sum += __shfl_xor(sum, 1, 64);
    sum += __shfl_xor(sum, 2, 64);
    if (c4 == 0) {
      float lse = logf(sum) + mx;
      sRed[r] = lse - sL[r * 100 + targets[b * 64 + r]];
    }
  }
  __syncthreads();
  if (wave == 0) {
    float v = sRed[lane];
#pragma unroll
    for (int m = 32; m >= 1; m >>= 1) v += __shfl_xor(v, m, 64);
    if (lane == 0) loss_part[b] = v;
  }
}

__global__ void loss_reduce(const float* __restrict__ loss_part, float* __restrict__ out_loss) {
  __shared__ float red[256];
  int t = threadIdx.x;
  float s = 0.f;
  for (int i = t; i < 4096; i += 256) s += loss_part[i];
  red[t] = s;
  __syncthreads();
  for (int k = 128; k >= 1; k >>= 1) {
    if (t < k) red[t] += red[t + k];
    __syncthreads();
  }
  if (t == 0) out_loss[0] = red[0] * (1.f / 262144.f);
}

extern "C" void kernel_launch(void* const* d_in, const int* in_sizes, int n_in,
                              void* d_out, int out_size, void* d_ws, size_t ws_size,
                              hipStream_t stream) {
  (void)in_sizes; (void)n_in; (void)ws_size;
  const int* idx      = (const int*)d_in[0];
  const int* targets  = (const int*)d_in[1];
  const float* tok_emb = (const float*)d_in[2];
  const float* pos_emb = (const float*)d_in[3];
  const float* Wq = (const float*)d_in[4];
  const float* Wk = (const float*)d_in[5];
  const float* Wv = (const float*)d_in[6];
  const float* Wo = (const float*)d_in[7];
  const float* bo = (const float*)d_in[8];
  const float* ln1_g = (const float*)d_in[9];
  const float* ln1_b = (const float*)d_in[10];
  const float* ln2_g = (const float*)d_in[11];
  const float* ln2_b = (const float*)d_in[12];
  const float* W1 = (const float*)d_in[13];
  const float* b1 = (const float*)d_in[14];
  const float* W2 = (const float*)d_in[15];
  const float* b2 = (const float*)d_in[16];
  const float* lnf_g = (const float*)d_in[17];
  const float* lnf_b = (const float*)d_in[18];
  const float* lm_b = (const float*)d_in[19];

  short* wsb = (short*)d_ws;
  float* loss_part = (float*)((char*)d_ws + (size_t)WS_END * 2);
  float* out = (float*)d_out;

  prep_weights<<<1560, PREP_THR, 0, stream>>>(tok_emb, Wq, Wk, Wv, Wo, W1, W2, wsb);
  lm_forward<<<4096, 256, 0, stream>>>(idx, targets, tok_emb, pos_emb, bo,
                                       ln1_g, ln1_b, ln2_g, ln2_b, b1, b2,
                                       lnf_g, lnf_b, lm_b, wsb, out, loss_part);
  loss_reduce<<<1, 256, 0, stream>>>(loss_part, out + (out_size - 1));
}

// Round 16
// 785.372 us; speedup vs baseline: 4.3873x; 1.0344x over previous
//
#include <hip/hip_runtime.h>
#include <hip/hip_bf16.h>
#include <math.h>

// Problem constants: V=96, D=128, T=64, H=8, HD=16, FF=512, L=4, B=4096
#define PREP_THR 512

typedef __attribute__((ext_vector_type(8))) short bf16x8;
typedef __attribute__((ext_vector_type(4))) short bf16x4;
typedef __attribute__((ext_vector_type(4))) float f32x4;

#define MFMA32(a, b, c) __builtin_amdgcn_mfma_f32_16x16x32_bf16((a), (b), (c), 0, 0, 0)

#if defined(__has_builtin)
#if __has_builtin(__builtin_amdgcn_mfma_f32_16x16x16bf16_1k)
#define HAVE_MFMA16 1
#endif
#endif
#ifdef HAVE_MFMA16
#define MFMA16(a, b, c) __builtin_amdgcn_mfma_f32_16x16x16bf16_1k((a), (b), (c), 0, 0, 0)
#else
__device__ __forceinline__ f32x4 mfma16_fb(bf16x4 a, bf16x4 b, f32x4 c) {
  asm volatile("s_nop 1\n\tv_mfma_f32_16x16x16_bf16 %0, %1, %2, %0\n\ts_nop 7\n\ts_nop 7"
               : "+v"(c) : "v"(a), "v"(b));
  return c;
}
#define MFMA16(a, b, c) mfma16_fb((a), (b), (c))
#endif

// ---- workspace layout (bf16 element offsets) ----
// Weights bf16, TILE-MAJOR swizzle: dst[(n>>4)][(k>>3)][n&15][k&7]
//   flat = (n>>4)*((K/8)*128) + (k>>3)*128 + (n&15)*8 + (k&7)
// -> B-fragment load addr = ct*ctS + (ks*4+lg)*128 + lr*8 : inner strides 256B/1KB
//    (fit global-load offset imm), wave reads contiguous 1KB (coalesced).
#define WS_EMB 0                      // [96][128]   ctS=2048
#define WS_WQ  12288                  // 4x[128][128] ctS=2048
#define WS_WK  (WS_WQ + 65536)
#define WS_WV  (WS_WK + 65536)
#define WS_WO  (WS_WV + 65536)
#define WS_W1  (WS_WO + 65536)        // 4x[512][128] ctS=2048
#define WS_W2  (WS_W1 + 262144)       // 4x[128][512] ctS=8192
#define WS_END (WS_W2 + 262144)

__device__ __forceinline__ short f2bf(float f) {
  union { __hip_bfloat16 h; unsigned short s; } u;
  u.h = __float2bfloat16(f);
  return (short)u.s;
}
__device__ __forceinline__ bf16x4 pk4(f32x4 v) {
  bf16x4 r;
  r[0] = f2bf(v[0]); r[1] = f2bf(v[1]); r[2] = f2bf(v[2]); r[3] = f2bf(v[3]);
  return r;
}
__device__ __forceinline__ float gelu1(float x) {
  float y = x * __builtin_fmaf(0.0356774081f, x * x, 0.7978845608f);
  return x * __builtin_amdgcn_rcpf(1.f + exp2f(-2.885390082f * y));
}

__global__ void prep_weights(const float* __restrict__ tok_emb,
                             const float* __restrict__ Wq, const float* __restrict__ Wk,
                             const float* __restrict__ Wv, const float* __restrict__ Wo,
                             const float* __restrict__ W1, const float* __restrict__ W2,
                             short* __restrict__ wsb) {
  int i = blockIdx.x * PREP_THR + threadIdx.x;
  if (i < 12288) {                       // tok_emb [96][128]
    int n = i >> 7, k = i & 127;
    wsb[WS_EMB + (n >> 4) * 2048 + (k >> 3) * 128 + (n & 15) * 8 + (k & 7)] =
        f2bf(tok_emb[i]);
    return;
  }
  i -= 12288;
  if (i < 262144) {                      // Wq,Wk,Wv,Wo: [4][128][128] each
    int tensor = i >> 16;
    int rem = i & 65535;
    int l = rem >> 14;
    int w = rem & 16383;
    int n = w >> 7, k = w & 127;
    const float* src = tensor == 0 ? Wq : tensor == 1 ? Wk : tensor == 2 ? Wv : Wo;
    wsb[WS_WQ + tensor * 65536 + l * 16384 +
        (n >> 4) * 2048 + (k >> 3) * 128 + (n & 15) * 8 + (k & 7)] = f2bf(src[rem]);
    return;
  }
  i -= 262144;
  if (i < 262144) {                      // W1 [4][512][128]
    int l = i >> 16;
    int w = i & 65535;
    int n = w >> 7, k = w & 127;
    wsb[WS_W1 + l * 65536 +
        (n >> 4) * 2048 + (k >> 3) * 128 + (n & 15) * 8 + (k & 7)] = f2bf(W1[i]);
    return;
  }
  i -= 262144;
  if (i < 262144) {                      // W2 [4][128][512]
    int l = i >> 16;
    int w = i & 65535;
    int n = w >> 9, k = w & 511;
    wsb[WS_W2 + l * 65536 +
        (n >> 4) * 8192 + (k >> 3) * 128 + (n & 15) * 8 + (k & 7)] = f2bf(W2[i]);
  }
}

// One block per sequence, 256 threads = 4 waves; 2 blocks/CU (the only proven
// spill-free operating point). R15 structure + tile-major weight addressing
// (small inner strides -> offset-immediate folding, less VALU addr math) +
// max-free CE. Wave owns 32 dims (2 heads).
// x[cg][n][r] = X^T[wave*32+cg*16+lg*4+r][16n+lr].
__global__ __launch_bounds__(256, 2)
void lm_forward(const int* __restrict__ idx, const int* __restrict__ targets,
                const float* __restrict__ tok_emb, const float* __restrict__ pos_emb,
                const float* __restrict__ bo, const float* __restrict__ ln1_g,
                const float* __restrict__ ln1_b, const float* __restrict__ ln2_g,
                const float* __restrict__ ln2_b, const float* __restrict__ b1,
                const float* __restrict__ b2, const float* __restrict__ lnf_g,
                const float* __restrict__ lnf_b, const float* __restrict__ lm_b,
                const short* __restrict__ wsb, float* __restrict__ out,
                float* __restrict__ loss_part) {
  __shared__ __align__(16) short sXn[64 * 136];      // 17408 B (LN out)
  __shared__ __align__(16) char region[33792];       // sAtt[64][136] / sH[64][264] / sL[64][100]f32
  __shared__ __align__(16) float sPart[4 * 64 * 2];  // 2048 B LN partials
  __shared__ float sRed[64];
  short* sAtt = (short*)region;
  short* sH = (short*)region;
  float* sL = (float*)region;

  const int b = blockIdx.x;
  const int tid = threadIdx.x;
  const int wave = tid >> 6;       // 0..3
  const int lane = tid & 63;
  const int lr = lane & 15;
  const int lg = lane >> 4;
  const f32x4 fz = {0.f, 0.f, 0.f, 0.f};
  const float KSC = 0.360673760f;  // 0.25 * log2(e)

  // ---- embedding: residual regs (wave owns dims wave*32 .. +31) ----
  f32x4 x[2][4];
#pragma unroll
  for (int cg = 0; cg < 2; ++cg)
#pragma unroll
    for (int n = 0; n < 4; ++n) {
      int t = 16 * n + lr;
      int dim = wave * 32 + cg * 16 + lg * 4;
      int tk = idx[b * 64 + t];
      x[cg][n] = *(const f32x4*)(tok_emb + tk * 128 + dim) +
                 *(const f32x4*)(pos_emb + t * 128 + dim);
    }

  // LN on reg residual; 2 barriers; writes sXn.
  auto ln = [&](const float* g, const float* be) {
    float s[4], s2[4];
#pragma unroll
    for (int n = 0; n < 4; ++n) {
      float a = 0.f, a2 = 0.f;
#pragma unroll
      for (int cg = 0; cg < 2; ++cg)
#pragma unroll
        for (int r = 0; r < 4; ++r) {
          float v = x[cg][n][r];
          a += v; a2 += v * v;
        }
      s[n] = a; s2[n] = a2;
    }
#pragma unroll
    for (int n = 0; n < 4; ++n) {
      s[n] += __shfl_xor(s[n], 16, 64);  s[n] += __shfl_xor(s[n], 32, 64);
      s2[n] += __shfl_xor(s2[n], 16, 64); s2[n] += __shfl_xor(s2[n], 32, 64);
    }
    if (lg == 0) {
#pragma unroll
      for (int n = 0; n < 4; ++n) {
        float2 p; p.x = s[n]; p.y = s2[n];
        *(float2*)(sPart + (wave * 64 + 16 * n + lr) * 2) = p;
      }
    }
    __syncthreads();
    f32x4 g4[2], b4[2];
#pragma unroll
    for (int cg = 0; cg < 2; ++cg) {
      int dim = wave * 32 + cg * 16 + lg * 4;
      g4[cg] = *(const f32x4*)(g + dim);
      b4[cg] = *(const f32x4*)(be + dim);
    }
#pragma unroll
    for (int n = 0; n < 4; ++n) {
      float S = 0.f, S2 = 0.f;
#pragma unroll
      for (int w = 0; w < 4; ++w) {
        float2 p = *(const float2*)(sPart + (w * 64 + 16 * n + lr) * 2);
        S += p.x; S2 += p.y;
      }
      float mean = S * 0.0078125f;
      float rstd = rsqrtf(__builtin_fmaf(-mean, mean, S2 * 0.0078125f) + 1e-5f);
#pragma unroll
      for (int cg = 0; cg < 2; ++cg) {
        f32x4 o;
#pragma unroll
        for (int c = 0; c < 4; ++c)
          o[c] = __builtin_fmaf((x[cg][n][c] - mean) * rstd, g4[cg][c], b4[cg][c]);
        *(bf16x4*)(sXn + (16 * n + lr) * 136 + wave * 32 + cg * 16 + lg * 4) = pk4(o);
      }
    }
    __syncthreads();
  };

#pragma unroll 1
  for (int l = 0; l < 4; ++l) {
    ln(ln1_g + l * 128, ln1_b + l * 128);

    // ---- QKV + attention, per head (wave owns heads 2*wave, 2*wave+1) ----
    const short* wq = wsb + WS_WQ + l * 16384;
    const short* wk = wsb + WS_WK + l * 16384;
    const short* wv = wsb + WS_WV + l * 16384;
#pragma unroll
    for (int hs = 0; hs < 2; ++hs) {
      const int h = wave * 2 + hs;
      f32x4 aq[4], ak[4], av[4];
#pragma unroll
      for (int n = 0; n < 4; ++n) { aq[n] = fz; ak[n] = fz; av[n] = fz; }
      const int wbase = h * 2048 + lg * 128 + lr * 8;
#pragma unroll
      for (int ks = 0; ks < 4; ++ks) {
        bf16x8 xf[4];
#pragma unroll
        for (int n = 0; n < 4; ++n)
          xf[n] = *(const bf16x8*)(sXn + (16 * n + lr) * 136 + ks * 32 + lg * 8);
        int wo_ = wbase + ks * 512;
        bf16x8 qw = *(const bf16x8*)(wq + wo_);
        bf16x8 kw = *(const bf16x8*)(wk + wo_);
        bf16x8 vw = *(const bf16x8*)(wv + wo_);
#pragma unroll
        for (int n = 0; n < 4; ++n) {
          aq[n] = MFMA32(qw, xf[n], aq[n]);
          ak[n] = MFMA32(kw, xf[n], ak[n]);
          av[n] = MFMA32(xf[n], vw, av[n]);
        }
      }
      bf16x4 qf[4], kf[4], vf[4];
#pragma unroll
      for (int n = 0; n < 4; ++n) {
        qf[n] = pk4(aq[n] * KSC);
        kf[n] = pk4(ak[n]);
        vf[n] = pk4(av[n]);
      }
      // in-register attention: max-free exp2 softmax, deferred 1/Z, causal skip
      f32x4 sc[4][4];
#pragma unroll
      for (int n = 0; n < 4; ++n)
#pragma unroll
        for (int m = 0; m <= n; ++m)
          sc[m][n] = MFMA16(kf[m], qf[n], fz);
#pragma unroll
      for (int n = 0; n < 4; ++n) {
#pragma unroll
        for (int r = 0; r < 4; ++r)
          if (lg * 4 + r > lr) sc[n][n][r] = -1e30f;
        float sum = 0.f;
#pragma unroll
        for (int m = 0; m <= n; ++m)
#pragma unroll
          for (int r = 0; r < 4; ++r) {
            float p = exp2f(sc[m][n][r]);   // bounded: |sc| <= ~46
            sc[m][n][r] = p;
            sum += p;
          }
        f32x4 ao = fz;
#pragma unroll
        for (int m = 0; m <= n; ++m) {
          bf16x4 pf = pk4(sc[m][n]);
          ao = MFMA16(vf[m], pf, ao);
        }
        sum += __shfl_xor(sum, 16, 64);
        sum += __shfl_xor(sum, 32, 64);
        float rinv = __builtin_amdgcn_rcpf(sum);
        *(bf16x4*)(sAtt + (16 * n + lr) * 136 + h * 16 + lg * 4) = pk4(ao * rinv);
      }
    }
    __syncthreads();

    // ---- Wo: accumulate directly into residual regs (cols wave*32..+31) ----
    {
      const short* wo = wsb + WS_WO + l * 16384;
      const int wbase = wave * 4096 + lg * 128 + lr * 8;
#pragma unroll
      for (int ks = 0; ks < 4; ++ks) {
        bf16x8 af[4];
#pragma unroll
        for (int n = 0; n < 4; ++n)
          af[n] = *(const bf16x8*)(sAtt + (16 * n + lr) * 136 + ks * 32 + lg * 8);
#pragma unroll
        for (int cg = 0; cg < 2; ++cg) {
          bf16x8 wf = *(const bf16x8*)(wo + wbase + cg * 2048 + ks * 512);
#pragma unroll
          for (int n = 0; n < 4; ++n) x[cg][n] = MFMA32(wf, af[n], x[cg][n]);
        }
      }
#pragma unroll
      for (int cg = 0; cg < 2; ++cg) {
        f32x4 bo4 = *(const f32x4*)(bo + l * 128 + wave * 32 + cg * 16 + lg * 4);
#pragma unroll
        for (int n = 0; n < 4; ++n) x[cg][n] = x[cg][n] + bo4;
      }
    }

    ln(ln2_g + l * 128, ln2_b + l * 128);

    // ---- FF: 2 hidden chunks of 256; FF1 in 2 g-passes (acc 32);
    //      FF2 accumulates directly into residual regs ----
    {
      const short* w1 = wsb + WS_W1 + l * 65536;
      const short* w2 = wsb + WS_W2 + l * 65536;
#pragma unroll 1
      for (int c = 0; c < 2; ++c) {
        const int w1base = (c * 16 + wave * 4) * 2048 + lg * 128 + lr * 8;
#pragma unroll 1
        for (int g2 = 0; g2 < 2; ++g2) {
          f32x4 a1[2][4];
#pragma unroll
          for (int gg = 0; gg < 2; ++gg)
#pragma unroll
            for (int n = 0; n < 4; ++n) a1[gg][n] = fz;
#pragma unroll
          for (int ks = 0; ks < 4; ++ks) {
            bf16x8 xf[4];
#pragma unroll
            for (int n = 0; n < 4; ++n)
              xf[n] = *(const bf16x8*)(sXn + (16 * n + lr) * 136 + ks * 32 + lg * 8);
#pragma unroll
            for (int gg = 0; gg < 2; ++gg) {
              bf16x8 wf = *(const bf16x8*)(w1 + w1base + (g2 * 2 + gg) * 2048 + ks * 512);
#pragma unroll
              for (int n = 0; n < 4; ++n) a1[gg][n] = MFMA32(wf, xf[n], a1[gg][n]);
            }
          }
#pragma unroll
          for (int gg = 0; gg < 2; ++gg) {
            f32x4 b1v = *(const f32x4*)(b1 + l * 512 + c * 256 + wave * 64 +
                                        (g2 * 2 + gg) * 16 + lg * 4);
#pragma unroll
            for (int n = 0; n < 4; ++n) {
              f32x4 hv;
#pragma unroll
              for (int r = 0; r < 4; ++r) hv[r] = gelu1(a1[gg][n][r] + b1v[r]);
              *(bf16x4*)(sH + (16 * n + lr) * 264 + wave * 64 +
                         (g2 * 2 + gg) * 16 + lg * 4) = pk4(hv);
            }
          }
        }
        __syncthreads();
        const int w2base = wave * 8192 + c * 4096 + lg * 128 + lr * 8;
#pragma unroll
        for (int ks = 0; ks < 8; ++ks) {
          bf16x8 hf[4];
#pragma unroll
          for (int n = 0; n < 4; ++n)
            hf[n] = *(const bf16x8*)(sH + (16 * n + lr) * 264 + ks * 32 + lg * 8);
#pragma unroll
          for (int cg = 0; cg < 2; ++cg) {
            // cg selects output-dim tile: W2 ct = wave*... wait: ct = (wave*32+cg*16+lr)>>4
            bf16x8 wf = *(const bf16x8*)(w2 + (wave * 2 + cg) * 8192 + c * 4096 +
                                         ks * 512 + lg * 128 + lr * 8);
#pragma unroll
            for (int n = 0; n < 4; ++n) x[cg][n] = MFMA32(wf, hf[n], x[cg][n]);
          }
        }
        (void)w2base;
        if (c == 0) __syncthreads();
      }
#pragma unroll
      for (int cg = 0; cg < 2; ++cg) {
        f32x4 b2v = *(const f32x4*)(b2 + l * 128 + wave * 32 + cg * 16 + lg * 4);
#pragma unroll
        for (int n = 0; n < 4; ++n) x[cg][n] = x[cg][n] + b2v;
      }
    }
  }

  // ---- final LN ----
  ln(lnf_g, lnf_b);

  // ---- logits: vocab tiles {wave} + {wave+4 if wave<2} ----
  {
    auto do_tile = [&](int vt) {
      f32x4 al[4];
#pragma unroll
      for (int n = 0; n < 4; ++n) al[n] = fz;
#pragma unroll
      for (int ks = 0; ks < 4; ++ks) {
        bf16x8 ef = *(const bf16x8*)(wsb + WS_EMB + vt * 2048 + ks * 512 +
                                     lg * 128 + lr * 8);
#pragma unroll
        for (int n = 0; n < 4; ++n) {
          bf16x8 xf = *(const bf16x8*)(sXn + (16 * n + lr) * 136 + ks * 32 + lg * 8);
          al[n] = MFMA32(ef, xf, al[n]);
        }
      }
      f32x4 lb = *(const f32x4*)(lm_b + vt * 16 + lg * 4);
#pragma unroll
      for (int n = 0; n < 4; ++n) {
        f32x4 v = al[n] + lb;
        int t = 16 * n + lr;
        *(f32x4*)(out + ((size_t)b * 64 + t) * 96 + vt * 16 + lg * 4) = v;
        *(f32x4*)(sL + t * 100 + vt * 16 + lg * 4) = v;
      }
    };
    do_tile(wave);
    if (wave < 2) do_tile(wave + 4);
  }
  __syncthreads();

  // ---- per-row cross-entropy (4 threads/row, 24 cols each; max-free, logits small) ----
  {
    int r = tid >> 2, c4 = tid & 3;
    const float* lrow = sL + r * 100 + c4 * 24;
    float sum = 0.f;
#pragma unroll
    for (int j = 0; j < 24; ++j) sum += __expf(lrow[j]);
    sum += __shfl_xor(sum, 1, 64);
    sum += __shfl_xor(sum, 2, 64);
    if (c4 == 0) {
      float lse = logf(sum);
      sRed[r] = lse - sL[r * 100 + targets[b * 64 + r]];
    }
  }
  __syncthreads();
  if (wave == 0) {
    float v = sRed[lane];
#pragma unroll
    for (int m = 32; m >= 1; m >>= 1) v += __shfl_xor(v, m, 64);
    if (lane == 0) loss_part[b] = v;
  }
}

__global__ void loss_reduce(const float* __restrict__ loss_part, float* __restrict__ out_loss) {
  __shared__ float red[256];
  int t = threadIdx.x;
  float s = 0.f;
  for (int i = t; i < 4096; i += 256) s += loss_part[i];
  red[t] = s;
  __syncthreads();
  for (int k = 128; k >= 1; k >>= 1) {
    if (t < k) red[t] += red[t + k];
    __syncthreads();
  }
  if (t == 0) out_loss[0] = red[0] * (1.f / 262144.f);
}

extern "C" void kernel_launch(void* const* d_in, const int* in_sizes, int n_in,
                              void* d_out, int out_size, void* d_ws, size_t ws_size,
                              hipStream_t stream) {
  (void)in_sizes; (void)n_in; (void)ws_size;
  const int* idx      = (const int*)d_in[0];
  const int* targets  = (const int*)d_in[1];
  const float* tok_emb = (const float*)d_in[2];
  const float* pos_emb = (const float*)d_in[3];
  const float* Wq = (const float*)d_in[4];
  const float* Wk = (const float*)d_in[5];
  const float* Wv = (const float*)d_in[6];
  const float* Wo = (const float*)d_in[7];
  const float* bo = (const float*)d_in[8];
  const float* ln1_g = (const float*)d_in[9];
  const float* ln1_b = (const float*)d_in[10];
  const float* ln2_g = (const float*)d_in[11];
  const float* ln2_b = (const float*)d_in[12];
  const float* W1 = (const float*)d_in[13];
  const float* b1 = (const float*)d_in[14];
  const float* W2 = (const float*)d_in[15];
  const float* b2 = (const float*)d_in[16];
  const float* lnf_g = (const float*)d_in[17];
  const float* lnf_b = (const float*)d_in[18];
  const float* lm_b = (const float*)d_in[19];

  short* wsb = (short*)d_ws;
  float* loss_part = (float*)((char*)d_ws + (size_t)WS_END * 2);
  float* out = (float*)d_out;

  prep_weights<<<1560, PREP_THR, 0, stream>>>(tok_emb, Wq, Wk, Wv, Wo, W1, W2, wsb);
  lm_forward<<<4096, 256, 0, stream>>>(idx, targets, tok_emb, pos_emb, bo,
                                       ln1_g, ln1_b, ln2_g, ln2_b, b1, b2,
                                       lnf_g, lnf_b, lm_b, wsb, out, loss_part);
  loss_reduce<<<1, 256, 0, stream>>>(loss_part, out + (out_size - 1));
}